// Round 6
// baseline (92.816 us; speedup 1.0000x reference)
//
#include <hip/hip_runtime.h>
#include <math.h>

// Diffusion loss, two kernels (r2/r5-verified structure; r3/r4 fusion both
// regressed — serial Jacobi stays OFF the per-block critical path, no
// cross-block waits on ws).
//   k_bond_stats: 64x64 triangle tiles (528/batch, 2112 blocks at B=4,N=2048)
//                 -> 8.25 blocks/CU: fine-grained balance (r2's 128-tiles left
//                 32 CUs serializing 3 tiles = straggler critical path), and
//                 high occupancy to overlap the 1/4-rate sqrt trans pipe.
//                 Diagonal tiles carry the stats duty (wave 0 = all 64 rows).
//   k_tail2:      distributed tail — every block redundantly reduces stats and
//                 runs the f64 Jacobi Kabsch (4 sweeps), slice of align pass +
//                 bond slot reduce, wait-free f64 atomicAdd + ticket finalize.
//
// ws layout (doubles):
//   [0 .. B*CTILES*16)        stats partials, slot (b*CTILES+bx)*16+k (diag tiles)
//   [.. +B*T)                 bond partials, slot = b*T + tile
//   [.. +3)                   finals: [0]=alignAcc [1]=bondAcc [2]=ticket (uint)
// finals zeroed by k_bond_stats block (0,0); kernel boundary orders vs k_tail2.

#define RT 256      // threads per block
#define TSZ 64      // tile edge (rows == cols; triangle decomposition)
#define MAXB 8

__global__ __launch_bounds__(RT, 8)
void k_bond_stats(const float* __restrict__ pred, const float* __restrict__ gt,
                  const float* __restrict__ w, double* __restrict__ ws,
                  int N, int B, int T, int CTILES, unsigned total) {
    const int b    = blockIdx.y;
    const int tid  = threadIdx.x;
    const int lane = tid & 63, wave = tid >> 6;

    // decode upper-triangle tile (bx, by>=bx) from linear id: closed form + fix
    int bx;
    {
        const int rem = blockIdx.x;
        const float tc = 2.0f*CTILES + 1.0f;
        bx = (int)((tc - sqrtf(tc*tc - 8.0f*(float)rem)) * 0.5f);
        if (bx < 0) bx = 0;
        // offset(x) = x*CTILES - x*(x-1)/2
        while ((bx+1)*CTILES - (((bx+1)*bx) >> 1) <= rem) bx++;
        while (bx*CTILES - ((bx*(bx-1)) >> 1) > rem) bx--;
    }
    const int by = bx + (blockIdx.x - (bx*CTILES - ((bx*(bx-1)) >> 1)));
    const int r0 = bx * TSZ, c0 = by * TSZ;

    double* statsSlot = ws;                               // B*CTILES*16
    double* bondSlot  = ws + (size_t)B * CTILES * 16;     // B*T
    if (blockIdx.x == 0 && blockIdx.y == 0 && tid == 0) {
        double* fin = bondSlot + total;
        fin[0] = 0.0; fin[1] = 0.0; fin[2] = 0.0;
    }

    const float* p  = pred + (size_t)b * N * 3;
    const float* g  = gt   + (size_t)b * N * 3;
    const float* wb = w    + (size_t)b * N;

    __shared__ float4 sp4[TSZ], sg4[TSZ];
    __shared__ double shred[4];

    const int rrow = tid & (TSZ - 1);     // row within tile (== lane)
    const int q    = tid >> 6;            // col-quarter (== wave): cols [q*16, q*16+16)
    const int n    = r0 + rrow;
    const bool row_ok = (n < N);
    float px=0.f,py=0.f,pz=0.f,gx=0.f,gy=0.f,gz=0.f,wn=0.f;
    if (row_ok) {
        px = p[3*n]; py = p[3*n+1]; pz = p[3*n+2];
        gx = g[3*n]; gy = g[3*n+1]; gz = g[3*n+2];
        wn = wb[n];
    }

    // stage cols: threads [0,64) -> pred+w, [64,128) -> gt
    if (tid < 2*TSZ) {
        const int i = tid & (TSZ - 1);
        const int m = c0 + i;
        if (tid < TSZ) {
            float4 v = make_float4(0.f,0.f,0.f,0.f);
            if (m < N) v = make_float4(p[3*m], p[3*m+1], p[3*m+2], wb[m]);
            sp4[i] = v;
        } else {
            float4 v = make_float4(0.f,0.f,0.f,0.f);
            if (m < N) v = make_float4(g[3*m], g[3*m+1], g[3*m+2], 0.f);
            sg4[i] = v;
        }
    }
    __syncthreads();

    // bond: strict upper triangle (m > n), counted twice; row weight factored out
    float acc = 0.f;
    const int ib = q * (TSZ/4);
    if (by > bx) {                        // whole tile strictly above diagonal
        #pragma unroll 4
        for (int j = 0; j < TSZ/4; j++) {
            const int i = ib + j;
            float4 cp = sp4[i], cg = sg4[i];
            float dxp=px-cp.x, dyp=py-cp.y, dzp=pz-cp.z;
            float dxg=gx-cg.x, dyg=gy-cg.y, dzg=gz-cg.z;
            float dp = sqrtf(dxp*dxp+dyp*dyp+dzp*dzp);
            float dg = sqrtf(dxg*dxg+dyg*dyg+dzg*dzg);
            float dd = dp - dg;
            acc = fmaf(cp.w, dd*dd, acc);
        }
    } else {                              // diagonal tile: predicate i > rrow
        #pragma unroll 4
        for (int j = 0; j < TSZ/4; j++) {
            const int i = ib + j;
            float4 cp = sp4[i], cg = sg4[i];
            float dxp=px-cp.x, dyp=py-cp.y, dzp=pz-cp.z;
            float dxg=gx-cg.x, dyg=gy-cg.y, dzg=gz-cg.z;
            float dp = sqrtf(dxp*dxp+dyp*dyp+dzp*dzp);
            float dg = sqrtf(dxg*dxg+dyg*dyg+dzg*dzg);
            float dd = dp - dg;
            float t  = cp.w * (dd*dd);
            acc += (i > rrow) ? t : 0.f;
        }
    }
    const float bond_f = 2.0f * wn * acc;

    // stats: diagonal tiles only; wave 0 holds all 64 rows of this tile exactly
    // once -> single-wave shuffle reduce, lane 0 stores (no LDS round-trip)
    if (bx == by && wave == 0) {
        double wd = wn;
        double pxd=px,pyd=py,pzd=pz, gxd=gx,gyd=gy,gzd=gz;
        double st[16] = {wd, wd*pxd, wd*pyd, wd*pzd, wd*gxd, wd*gyd, wd*gzd,
                         wd*pxd*gxd, wd*pxd*gyd, wd*pxd*gzd,
                         wd*pyd*gxd, wd*pyd*gyd, wd*pyd*gzd,
                         wd*pzd*gxd, wd*pzd*gyd, wd*pzd*gzd};
        #pragma unroll
        for (int off = 32; off > 0; off >>= 1) {
            #pragma unroll
            for (int k = 0; k < 16; k++) st[k] += __shfl_down(st[k], off, 64);
        }
        if (lane == 0) {
            #pragma unroll
            for (int k = 0; k < 16; k++)
                statsSlot[((size_t)b*CTILES + bx)*16 + k] = st[k];
        }
    }

    // bond block-reduce -> plain-store slot
    double bd = (double)bond_f;
    #pragma unroll
    for (int off = 32; off > 0; off >>= 1) bd += __shfl_down(bd, off, 64);
    if (lane == 0) shred[wave] = bd;
    __syncthreads();
    if (tid == 0)
        bondSlot[(size_t)blockIdx.y * T + blockIdx.x] =
            shred[0]+shred[1]+shred[2]+shred[3];
}

__global__ __launch_bounds__(RT, 1)
void k_tail2(const float* __restrict__ pred, const float* __restrict__ gt,
             const float* __restrict__ ht, const float* __restrict__ w,
             float* __restrict__ out, double* __restrict__ ws,
             int N, int B, int GX, unsigned total, int AG) {
    const int tid  = threadIdx.x;
    const int lane = tid & 63, wave = tid >> 6;
    const double* statsSlot = ws;
    const double* bondSlot  = ws + (size_t)B * GX * 16;
    double* fin = (double*)(bondSlot + total);

    __shared__ double sstat[MAXB][16];
    __shared__ float  sR[MAXB][15];   // [0..8]=R row-major, [9..11]=mup, [12..14]=mug
    __shared__ double sW[MAXB];
    __shared__ double shredA[4], shredB[4];

    // prefetch ht into thread-0 registers (static indices only — no scratch)
    float htv[MAXB];
    if (tid == 0) {
        #pragma unroll
        for (int b2 = 0; b2 < MAXB; b2++) htv[b2] = (b2 < B) ? ht[b2] : 0.f;
    }

    // stats reduce: thread (b*16+k) sums over GX row-tiles (every block, redundant)
    if (tid < B * 16) {
        int bb = tid >> 4, k = tid & 15;
        double acc = 0.0;
        for (int j = 0; j < GX; j++) acc += statsSlot[((size_t)bb*GX + j)*16 + k];
        sstat[bb][k] = acc;
    }

    // bond slot slice reduce (issued before the Jacobi barrier — latency hidden)
    double bsum = 0.0;
    for (unsigned i = (unsigned)blockIdx.x * RT + tid; i < total; i += (unsigned)AG * RT)
        bsum += bondSlot[i];

    // prefetch this thread's align point before the barrier (hides HBM latency
    // under the serial f64 Jacobi chain)
    const int ptTotal = B * N;
    const int stride  = AG * RT;
    const int pt0     = blockIdx.x * RT + tid;
    const bool have0  = (pt0 < ptTotal);
    float px=0.f,py=0.f,pz=0.f,qx=0.f,qy=0.f,qz=0.f,wn=0.f;
    int b0 = 0;
    if (have0) {
        b0 = pt0 / N; int n0 = pt0 - b0 * N;
        const float* pp = pred + (size_t)b0 * N * 3;
        const float* gg = gt   + (size_t)b0 * N * 3;
        px = pp[3*n0]; py = pp[3*n0+1]; pz = pp[3*n0+2];
        qx = gg[3*n0]; qy = gg[3*n0+1]; qz = gg[3*n0+2];
        wn = w[(size_t)b0 * N + n0];
    }

    __syncthreads();   // sstat ready

    // per-batch Kabsch (f64, one thread each; redundant per block — free).
    // 4 sweeps = 12 rotations: machine precision for 3x3 symmetric.
    if (tid < B) {
        const double* s = sstat[tid];
        double W = s[0];
        double mup[3] = { s[1]/W, s[2]/W, s[3]/W };
        double mug[3] = { s[4]/W, s[5]/W, s[6]/W };
        double M[3][3];
        for (int i = 0; i < 3; i++)
            for (int j = 0; j < 3; j++)
                M[i][j] = s[7 + i*3 + j] - W * mup[i] * mug[j];
        double A[3][3];
        for (int i = 0; i < 3; i++)
            for (int j = 0; j < 3; j++) {
                double t = 0.0;
                for (int k = 0; k < 3; k++) t += M[k][i] * M[k][j];
                A[i][j] = t;
            }
        double V[3][3] = {{1,0,0},{0,1,0},{0,0,1}};
        for (int sweep = 0; sweep < 4; sweep++) {
            for (int pq = 0; pq < 3; pq++) {
                int pp_ = (pq == 2) ? 1 : 0;
                int qq_ = (pq == 0) ? 1 : 2;
                double apq = A[pp_][qq_];
                if (fabs(apq) < 1e-300) continue;
                double app = A[pp_][pp_], aqq = A[qq_][qq_];
                double theta = (aqq - app) / (2.0 * apq);
                double t = copysign(1.0, theta) / (fabs(theta) + sqrt(theta*theta + 1.0));
                double cj = 1.0 / sqrt(t*t + 1.0), sn = t * cj;
                A[pp_][pp_] = app - t * apq;
                A[qq_][qq_] = aqq + t * apq;
                A[pp_][qq_] = A[qq_][pp_] = 0.0;
                int r = 3 - pp_ - qq_;
                double arp = A[r][pp_], arq = A[r][qq_];
                A[r][pp_] = A[pp_][r] = cj*arp - sn*arq;
                A[r][qq_] = A[qq_][r] = sn*arp + cj*arq;
                for (int rr = 0; rr < 3; rr++) {
                    double vp = V[rr][pp_], vq = V[rr][qq_];
                    V[rr][pp_] = cj*vp - sn*vq;
                    V[rr][qq_] = sn*vp + cj*vq;
                }
            }
        }
        double d[3] = { A[0][0], A[1][1], A[2][2] };
        int idx[3] = {0, 1, 2};   // descending: det-fix flips smallest sv
        for (int i = 0; i < 2; i++)
            for (int j = i + 1; j < 3; j++)
                if (d[idx[j]] > d[idx[i]]) { int tt = idx[i]; idx[i] = idx[j]; idx[j] = tt; }
        double u[3][3], v[3][3];
        for (int i = 0; i < 3; i++) {
            int c_ = idx[i];
            double sv = sqrt(fmax(d[c_], 0.0));
            double inv = (sv > 1e-12) ? 1.0 / sv : 0.0;
            for (int r = 0; r < 3; r++) v[i][r] = V[r][c_];
            for (int r = 0; r < 3; r++) {
                double t = 0.0;
                for (int k = 0; k < 3; k++) t += M[r][k] * v[i][k];
                u[i][r] = t * inv;
            }
        }
        double detM = M[0][0]*(M[1][1]*M[2][2] - M[1][2]*M[2][1])
                    - M[0][1]*(M[1][0]*M[2][2] - M[1][2]*M[2][0])
                    + M[0][2]*(M[1][0]*M[2][1] - M[1][1]*M[2][0]);
        double sg2 = (detM < 0.0) ? -1.0 : 1.0;
        for (int r = 0; r < 3; r++)
            for (int cc2 = 0; cc2 < 3; cc2++)
                sR[tid][r*3+cc2] = (float)(u[0][r]*v[0][cc2] + u[1][r]*v[1][cc2]
                                           + sg2 * u[2][r]*v[2][cc2]);
        for (int i = 0; i < 3; i++) sR[tid][9 + i]  = (float)mup[i];
        for (int i = 0; i < 3; i++) sR[tid][12 + i] = (float)mug[i];
        sW[tid] = W;
    }
    __syncthreads();

    // align pass slice (f32 math, f64 accumulate); first point was prefetched
    double al = 0.0;
    if (have0) {
        const float* Rb = sR[b0];
        float x0 = qx - Rb[12], x1 = qy - Rb[13], x2 = qz - Rb[14];
        float ax = fmaf(Rb[0],x0, fmaf(Rb[1],x1, fmaf(Rb[2],x2, Rb[9])));
        float ay = fmaf(Rb[3],x0, fmaf(Rb[4],x1, fmaf(Rb[5],x2, Rb[10])));
        float az = fmaf(Rb[6],x0, fmaf(Rb[7],x1, fmaf(Rb[8],x2, Rb[11])));
        float ex = px-ax, ey = py-ay, ez = pz-az;
        al += (double)(wn * sqrtf(ex*ex + ey*ey + ez*ez));
    }
    for (int pt = pt0 + stride; pt < ptTotal; pt += stride) {
        int b2 = pt / N; int nn = pt - b2 * N;
        const float* pp = pred + (size_t)b2 * N * 3;
        const float* gg = gt   + (size_t)b2 * N * 3;
        const float* Rb = sR[b2];
        float x0 = gg[3*nn]-Rb[12], x1 = gg[3*nn+1]-Rb[13], x2 = gg[3*nn+2]-Rb[14];
        float ax = fmaf(Rb[0],x0, fmaf(Rb[1],x1, fmaf(Rb[2],x2, Rb[9])));
        float ay = fmaf(Rb[3],x0, fmaf(Rb[4],x1, fmaf(Rb[5],x2, Rb[10])));
        float az = fmaf(Rb[6],x0, fmaf(Rb[7],x1, fmaf(Rb[8],x2, Rb[11])));
        float ex = pp[3*nn]-ax, ey = pp[3*nn+1]-ay, ez = pp[3*nn+2]-az;
        al += (double)(w[(size_t)b2*N + nn] * sqrtf(ex*ex + ey*ey + ez*ez));
    }

    // block reduce both accumulators
    #pragma unroll
    for (int off = 32; off > 0; off >>= 1) {
        al   += __shfl_down(al,   off, 64);
        bsum += __shfl_down(bsum, off, 64);
    }
    if (lane == 0) { shredA[wave] = al; shredB[wave] = bsum; }
    __syncthreads();

    if (tid == 0) {
        double alB = shredA[0]+shredA[1]+shredA[2]+shredA[3];
        double bB  = shredB[0]+shredB[1]+shredB[2]+shredB[3];
        atomicAdd(&fin[0], alB);
        atomicAdd(&fin[1], bB);
        __threadfence();
        unsigned old = atomicAdd((unsigned int*)&fin[2], 1u);
        if (old == (unsigned)(AG - 1)) {
            // last block: coherent reads via atomic RMW of 0
            double at = atomicAdd(&fin[0], 0.0);
            double bt = atomicAdd(&fin[1], 0.0);
            double tw = 0.0, twp = 0.0;
            for (int b2 = 0; b2 < B; b2++) { double W = sW[b2]; tw += W; twp += W*W; }
            double loss = at / tw + bt / twp;    // ALPHA_BOND = 1
            #pragma unroll
            for (int b2 = 0; b2 < MAXB; b2++) {
                if (b2 < B) {
                    double h = (double)htv[b2];
                    out[b2] = (float)(((h*h + 256.0) / ((h + 16.0)*(h + 16.0))) * loss); // SIGMA=16
                }
            }
        }
    }
}

extern "C" void kernel_launch(void* const* d_in, const int* in_sizes, int n_in,
                              void* d_out, int out_size, void* d_ws, size_t ws_size,
                              hipStream_t stream) {
    const float* pred = (const float*)d_in[0];  // xpred_l [B,N,3]
    const float* gt   = (const float*)d_in[1];  // xGT_l   [B,N,3]
    const float* ht   = (const float*)d_in[2];  // ht      [B]
    const float* w    = (const float*)d_in[3];  // w_l     [B,N]
    int B = in_sizes[2];
    int N = in_sizes[3] / B;
    double* ws = (double*)d_ws;
    float* out = (float*)d_out;

    int CTILES = (N + TSZ - 1) / TSZ;            // row-tiles == col-tiles (32)
    int T = CTILES * (CTILES + 1) / 2;           // upper-triangle tiles/batch (528)
    unsigned total = (unsigned)(B * T);          // bond slots (2112)

    int ag = (B * N + RT - 1) / RT;              // one align point per thread
    if (ag > 64) ag = 64;
    if (ag < 1)  ag = 1;

    k_bond_stats<<<dim3(T, B), dim3(RT), 0, stream>>>(pred, gt, w, ws, N, B, T, CTILES, total);
    k_tail2<<<dim3(ag), dim3(RT), 0, stream>>>(pred, gt, ht, w, out, ws, N, B, CTILES, total, ag);
}

// Round 7
// 90.487 us; speedup vs baseline: 1.0257x; 1.0257x over previous
//
#include <hip/hip_runtime.h>
#include <math.h>

// Diffusion loss, two kernels (r5-measured-best structure: 128-tiles, 4-sweep
// Jacobi; r3/r4 fusion regressed; r6's 64-tiles + GX=32 tail was neutral-worse
// with a 41us latency outlier in k_tail2's stats loop).
//   k_bond_stats: triangle-only 128x128 tiles (136/batch), 2 threads/row x 64
//                 cols. Diagonal tiles carry stats duty.
//   k_tail2:      distributed tail; stats-reduce split 4-ways per (b,k) so the
//                 pre-Jacobi load chain is 4 overlapped loads/thread (was 16
//                 serial-ish cold loads — the r6 outlier's mechanism at 32).
//
// ws layout (doubles):
//   [0 .. B*CTILES*16)        stats partials, slot (b*CTILES+bx)*16+k (diag tiles)
//   [.. +B*T)                 bond partials, slot = b*T + tile
//   [.. +3)                   finals: [0]=alignAcc [1]=bondAcc [2]=ticket (uint)
// finals zeroed by k_bond_stats block (0,0); kernel boundary orders vs k_tail2.

#define RT 256      // threads per block
#define TR 128      // rows per tile (must equal TC for triangle decomposition)
#define TC 128      // cols per tile
#define MAXB 8

__global__ __launch_bounds__(RT, 4)
void k_bond_stats(const float* __restrict__ pred, const float* __restrict__ gt,
                  const float* __restrict__ w, double* __restrict__ ws,
                  int N, int B, int T, int CTILES, unsigned total) {
    const int b    = blockIdx.y;
    const int tid  = threadIdx.x;
    const int lane = tid & 63, wave = tid >> 6;

    // decode upper-triangle tile: row-tile bx, col-tile by >= bx
    int rem = blockIdx.x, bx = 0;
    while (rem >= CTILES - bx) { rem -= (CTILES - bx); bx++; }
    const int by = bx + rem;
    const int r0 = bx * TR, c0 = by * TC;

    double* statsSlot = ws;                               // B*CTILES*16
    double* bondSlot  = ws + (size_t)B * CTILES * 16;     // B*T
    if (blockIdx.x == 0 && blockIdx.y == 0 && tid == 0) {
        double* fin = bondSlot + total;
        fin[0] = 0.0; fin[1] = 0.0; fin[2] = 0.0;
    }

    const float* p  = pred + (size_t)b * N * 3;
    const float* g  = gt   + (size_t)b * N * 3;
    const float* wb = w    + (size_t)b * N;

    __shared__ float4 sp4[TC], sg4[TC];
    __shared__ double shred[4][16];

    const int rrow  = tid & (TR - 1);     // row within tile
    const int rhalf = tid >> 7;           // 0: cols [0,64)  1: cols [64,128)
    const int n     = r0 + rrow;
    const bool row_ok = (n < N);
    float px=0.f,py=0.f,pz=0.f,gx=0.f,gy=0.f,gz=0.f,wn=0.f;
    if (row_ok) {
        px = p[3*n]; py = p[3*n+1]; pz = p[3*n+2];
        gx = g[3*n]; gy = g[3*n+1]; gz = g[3*n+2];
        wn = wb[n];
    }

    // stage cols: first half of threads -> pred+w, second half -> gt
    {
        int i = tid & (TC - 1);
        int m = c0 + i;
        if (tid < TC) {
            float4 v = make_float4(0.f,0.f,0.f,0.f);
            if (m < N) v = make_float4(p[3*m], p[3*m+1], p[3*m+2], wb[m]);
            sp4[i] = v;
        } else {
            float4 v = make_float4(0.f,0.f,0.f,0.f);
            if (m < N) v = make_float4(g[3*m], g[3*m+1], g[3*m+2], 0.f);
            sg4[i] = v;
        }
    }
    __syncthreads();

    // bond: strict upper triangle (m > n), counted twice; row weight factored out
    float acc = 0.f;
    const int ib = rhalf * (TC / 2);
    if (by > bx) {                        // whole tile strictly above diagonal
        #pragma unroll 4
        for (int j = 0; j < TC/2; j++) {
            int i = ib + j;
            float4 cp = sp4[i], cg = sg4[i];
            float dxp=px-cp.x, dyp=py-cp.y, dzp=pz-cp.z;
            float dxg=gx-cg.x, dyg=gy-cg.y, dzg=gz-cg.z;
            float dp = sqrtf(dxp*dxp+dyp*dyp+dzp*dzp);
            float dg = sqrtf(dxg*dxg+dyg*dyg+dzg*dzg);
            float dd = dp - dg;
            acc = fmaf(cp.w, dd*dd, acc);
        }
    } else {                              // diagonal tile: predicate i > rrow
        #pragma unroll 4
        for (int j = 0; j < TC/2; j++) {
            int i = ib + j;
            float4 cp = sp4[i], cg = sg4[i];
            float dxp=px-cp.x, dyp=py-cp.y, dzp=pz-cp.z;
            float dxg=gx-cg.x, dyg=gy-cg.y, dzg=gz-cg.z;
            float dp = sqrtf(dxp*dxp+dyp*dyp+dzp*dzp);
            float dg = sqrtf(dxg*dxg+dyg*dyg+dzg*dzg);
            float dd = dp - dg;
            float t  = cp.w * (dd*dd);
            acc += (i > rrow) ? t : 0.f;
        }
    }
    float bond_f = 2.0f * wn * acc;

    // stats: diagonal tiles only; each row counted once (rhalf==0)
    if (bx == by) {
        double wd = (rhalf == 0) ? (double)wn : 0.0;
        double pxd=px,pyd=py,pzd=pz, gxd=gx,gyd=gy,gzd=gz;
        double st[16] = {wd, wd*pxd, wd*pyd, wd*pzd, wd*gxd, wd*gyd, wd*gzd,
                         wd*pxd*gxd, wd*pxd*gyd, wd*pxd*gzd,
                         wd*pyd*gxd, wd*pyd*gyd, wd*pyd*gzd,
                         wd*pzd*gxd, wd*pzd*gyd, wd*pzd*gzd};
        #pragma unroll
        for (int off = 32; off > 0; off >>= 1) {
            #pragma unroll
            for (int k = 0; k < 16; k++) st[k] += __shfl_down(st[k], off, 64);
        }
        if (lane == 0) {
            #pragma unroll
            for (int k = 0; k < 16; k++) shred[wave][k] = st[k];
        }
        __syncthreads();
        if (tid < 16)
            statsSlot[((size_t)b*CTILES + bx)*16 + tid] =
                shred[0][tid]+shred[1][tid]+shred[2][tid]+shred[3][tid];
        __syncthreads();   // shred reused below
    }

    // bond block-reduce -> plain-store slot
    double bd = (double)bond_f;
    #pragma unroll
    for (int off = 32; off > 0; off >>= 1) bd += __shfl_down(bd, off, 64);
    if (lane == 0) shred[wave][0] = bd;
    __syncthreads();
    if (tid == 0)
        bondSlot[(size_t)blockIdx.y * T + blockIdx.x] =
            shred[0][0]+shred[1][0]+shred[2][0]+shred[3][0];
}

__global__ __launch_bounds__(RT, 1)
void k_tail2(const float* __restrict__ pred, const float* __restrict__ gt,
             const float* __restrict__ ht, const float* __restrict__ w,
             float* __restrict__ out, double* __restrict__ ws,
             int N, int B, int GX, unsigned total, int AG) {
    const int tid  = threadIdx.x;
    const int lane = tid & 63, wave = tid >> 6;
    const double* statsSlot = ws;
    const double* bondSlot  = ws + (size_t)B * GX * 16;
    double* fin = (double*)(bondSlot + total);

    __shared__ double sstat[MAXB][16];
    __shared__ float  sR[MAXB][15];   // [0..8]=R row-major, [9..11]=mup, [12..14]=mug
    __shared__ double sW[MAXB];
    __shared__ double shredA[4], shredB[4];

    // prefetch ht into thread-0 registers (static indices only — no scratch)
    float htv[MAXB];
    if (tid == 0) {
        #pragma unroll
        for (int b2 = 0; b2 < MAXB; b2++) htv[b2] = (b2 < B) ? ht[b2] : 0.f;
    }

    // stats reduce, 4-way split per (b,k): thread = b*64 + k*4 + j, j in [0,4).
    // Each thread issues GX/4 independent loads (overlapped in the vmcnt
    // queue), then a 2-step shfl combine. This is the chain that gates the
    // Jacobi barrier — r6's long serial version produced a 41us outlier.
    {
        const int bb = tid >> 6;          // batch (B<=4 uses all 256 threads)
        const int k  = (tid >> 2) & 15;   // stat index
        const int j  = tid & 3;           // slice
        double acc = 0.0;
        if (bb < B) {
            for (int m = j; m < GX; m += 4)
                acc += statsSlot[((size_t)bb*GX + m)*16 + k];
        }
        acc += __shfl_down(acc, 2, 64);
        acc += __shfl_down(acc, 1, 64);
        if (bb < B && j == 0) sstat[bb][k] = acc;
    }

    // bond slot slice reduce (issued before the Jacobi barrier — latency hidden)
    double bsum = 0.0;
    for (unsigned i = (unsigned)blockIdx.x * RT + tid; i < total; i += (unsigned)AG * RT)
        bsum += bondSlot[i];

    // prefetch this thread's align point before the barrier (hides HBM latency
    // under the serial f64 Jacobi chain)
    const int ptTotal = B * N;
    const int stride  = AG * RT;
    const int pt0     = blockIdx.x * RT + tid;
    const bool have0  = (pt0 < ptTotal);
    float px=0.f,py=0.f,pz=0.f,qx=0.f,qy=0.f,qz=0.f,wn=0.f;
    int b0 = 0;
    if (have0) {
        b0 = pt0 / N; int n0 = pt0 - b0 * N;
        const float* pp = pred + (size_t)b0 * N * 3;
        const float* gg = gt   + (size_t)b0 * N * 3;
        px = pp[3*n0]; py = pp[3*n0+1]; pz = pp[3*n0+2];
        qx = gg[3*n0]; qy = gg[3*n0+1]; qz = gg[3*n0+2];
        wn = w[(size_t)b0 * N + n0];
    }

    __syncthreads();   // sstat ready

    // per-batch Kabsch (f64, one thread each; redundant per block — free).
    // 4 sweeps = 12 rotations: machine precision for 3x3 symmetric.
    if (tid < B) {
        const double* s = sstat[tid];
        double W = s[0];
        double mup[3] = { s[1]/W, s[2]/W, s[3]/W };
        double mug[3] = { s[4]/W, s[5]/W, s[6]/W };
        double M[3][3];
        for (int i = 0; i < 3; i++)
            for (int j = 0; j < 3; j++)
                M[i][j] = s[7 + i*3 + j] - W * mup[i] * mug[j];
        double A[3][3];
        for (int i = 0; i < 3; i++)
            for (int j = 0; j < 3; j++) {
                double t = 0.0;
                for (int k = 0; k < 3; k++) t += M[k][i] * M[k][j];
                A[i][j] = t;
            }
        double V[3][3] = {{1,0,0},{0,1,0},{0,0,1}};
        for (int sweep = 0; sweep < 4; sweep++) {
            for (int pq = 0; pq < 3; pq++) {
                int pp_ = (pq == 2) ? 1 : 0;
                int qq_ = (pq == 0) ? 1 : 2;
                double apq = A[pp_][qq_];
                if (fabs(apq) < 1e-300) continue;
                double app = A[pp_][pp_], aqq = A[qq_][qq_];
                double theta = (aqq - app) / (2.0 * apq);
                double t = copysign(1.0, theta) / (fabs(theta) + sqrt(theta*theta + 1.0));
                double cj = 1.0 / sqrt(t*t + 1.0), sn = t * cj;
                A[pp_][pp_] = app - t * apq;
                A[qq_][qq_] = aqq + t * apq;
                A[pp_][qq_] = A[qq_][pp_] = 0.0;
                int r = 3 - pp_ - qq_;
                double arp = A[r][pp_], arq = A[r][qq_];
                A[r][pp_] = A[pp_][r] = cj*arp - sn*arq;
                A[r][qq_] = A[qq_][r] = sn*arp + cj*arq;
                for (int rr = 0; rr < 3; rr++) {
                    double vp = V[rr][pp_], vq = V[rr][qq_];
                    V[rr][pp_] = cj*vp - sn*vq;
                    V[rr][qq_] = sn*vp + cj*vq;
                }
            }
        }
        double d[3] = { A[0][0], A[1][1], A[2][2] };
        int idx[3] = {0, 1, 2};   // descending: det-fix flips smallest sv
        for (int i = 0; i < 2; i++)
            for (int j = i + 1; j < 3; j++)
                if (d[idx[j]] > d[idx[i]]) { int tt = idx[i]; idx[i] = idx[j]; idx[j] = tt; }
        double u[3][3], v[3][3];
        for (int i = 0; i < 3; i++) {
            int c_ = idx[i];
            double sv = sqrt(fmax(d[c_], 0.0));
            double inv = (sv > 1e-12) ? 1.0 / sv : 0.0;
            for (int r = 0; r < 3; r++) v[i][r] = V[r][c_];
            for (int r = 0; r < 3; r++) {
                double t = 0.0;
                for (int k = 0; k < 3; k++) t += M[r][k] * v[i][k];
                u[i][r] = t * inv;
            }
        }
        double detM = M[0][0]*(M[1][1]*M[2][2] - M[1][2]*M[2][1])
                    - M[0][1]*(M[1][0]*M[2][2] - M[1][2]*M[2][0])
                    + M[0][2]*(M[1][0]*M[2][1] - M[1][1]*M[2][0]);
        double sg2 = (detM < 0.0) ? -1.0 : 1.0;
        for (int r = 0; r < 3; r++)
            for (int cc2 = 0; cc2 < 3; cc2++)
                sR[tid][r*3+cc2] = (float)(u[0][r]*v[0][cc2] + u[1][r]*v[1][cc2]
                                           + sg2 * u[2][r]*v[2][cc2]);
        for (int i = 0; i < 3; i++) sR[tid][9 + i]  = (float)mup[i];
        for (int i = 0; i < 3; i++) sR[tid][12 + i] = (float)mug[i];
        sW[tid] = W;
    }
    __syncthreads();

    // align pass slice (f32 math, f64 accumulate); first point was prefetched
    double al = 0.0;
    if (have0) {
        const float* Rb = sR[b0];
        float x0 = qx - Rb[12], x1 = qy - Rb[13], x2 = qz - Rb[14];
        float ax = fmaf(Rb[0],x0, fmaf(Rb[1],x1, fmaf(Rb[2],x2, Rb[9])));
        float ay = fmaf(Rb[3],x0, fmaf(Rb[4],x1, fmaf(Rb[5],x2, Rb[10])));
        float az = fmaf(Rb[6],x0, fmaf(Rb[7],x1, fmaf(Rb[8],x2, Rb[11])));
        float ex = px-ax, ey = py-ay, ez = pz-az;
        al += (double)(wn * sqrtf(ex*ex + ey*ey + ez*ez));
    }
    for (int pt = pt0 + stride; pt < ptTotal; pt += stride) {
        int b2 = pt / N; int nn = pt - b2 * N;
        const float* pp = pred + (size_t)b2 * N * 3;
        const float* gg = gt   + (size_t)b2 * N * 3;
        const float* Rb = sR[b2];
        float x0 = gg[3*nn]-Rb[12], x1 = gg[3*nn+1]-Rb[13], x2 = gg[3*nn+2]-Rb[14];
        float ax = fmaf(Rb[0],x0, fmaf(Rb[1],x1, fmaf(Rb[2],x2, Rb[9])));
        float ay = fmaf(Rb[3],x0, fmaf(Rb[4],x1, fmaf(Rb[5],x2, Rb[10])));
        float az = fmaf(Rb[6],x0, fmaf(Rb[7],x1, fmaf(Rb[8],x2, Rb[11])));
        float ex = pp[3*nn]-ax, ey = pp[3*nn+1]-ay, ez = pp[3*nn+2]-az;
        al += (double)(w[(size_t)b2*N + nn] * sqrtf(ex*ex + ey*ey + ez*ez));
    }

    // block reduce both accumulators
    #pragma unroll
    for (int off = 32; off > 0; off >>= 1) {
        al   += __shfl_down(al,   off, 64);
        bsum += __shfl_down(bsum, off, 64);
    }
    if (lane == 0) { shredA[wave] = al; shredB[wave] = bsum; }
    __syncthreads();

    if (tid == 0) {
        double alB = shredA[0]+shredA[1]+shredA[2]+shredA[3];
        double bB  = shredB[0]+shredB[1]+shredB[2]+shredB[3];
        atomicAdd(&fin[0], alB);
        atomicAdd(&fin[1], bB);
        __threadfence();
        unsigned old = atomicAdd((unsigned int*)&fin[2], 1u);
        if (old == (unsigned)(AG - 1)) {
            // last block: coherent reads via atomic RMW of 0
            double at = atomicAdd(&fin[0], 0.0);
            double bt = atomicAdd(&fin[1], 0.0);
            double tw = 0.0, twp = 0.0;
            for (int b2 = 0; b2 < B; b2++) { double W = sW[b2]; tw += W; twp += W*W; }
            double loss = at / tw + bt / twp;    // ALPHA_BOND = 1
            #pragma unroll
            for (int b2 = 0; b2 < MAXB; b2++) {
                if (b2 < B) {
                    double h = (double)htv[b2];
                    out[b2] = (float)(((h*h + 256.0) / ((h + 16.0)*(h + 16.0))) * loss); // SIGMA=16
                }
            }
        }
    }
}

extern "C" void kernel_launch(void* const* d_in, const int* in_sizes, int n_in,
                              void* d_out, int out_size, void* d_ws, size_t ws_size,
                              hipStream_t stream) {
    const float* pred = (const float*)d_in[0];  // xpred_l [B,N,3]
    const float* gt   = (const float*)d_in[1];  // xGT_l   [B,N,3]
    const float* ht   = (const float*)d_in[2];  // ht      [B]
    const float* w    = (const float*)d_in[3];  // w_l     [B,N]
    int B = in_sizes[2];
    int N = in_sizes[3] / B;
    double* ws = (double*)d_ws;
    float* out = (float*)d_out;

    int CTILES = (N + TC - 1) / TC;              // row-tiles == col-tiles (TR==TC)
    int T = CTILES * (CTILES + 1) / 2;           // upper-triangle tiles per batch
    unsigned total = (unsigned)(B * T);

    int ag = (B * N + RT - 1) / RT;              // one align point per thread
    if (ag > 64) ag = 64;
    if (ag < 1)  ag = 1;

    k_bond_stats<<<dim3(T, B), dim3(RT), 0, stream>>>(pred, gt, w, ws, N, B, T, CTILES, total);
    k_tail2<<<dim3(ag), dim3(RT), 0, stream>>>(pred, gt, ht, w, out, ws, N, B, CTILES, total, ag);
}